// Round 4
// baseline (372.705 us; speedup 1.0000x reference)
//
#include <hip/hip_runtime.h>
#include <hip/hip_cooperative_groups.h>

namespace cg = cooperative_groups;

#define IMG_H 512
#define IMG_W 512
#define NGAUSS 10000
#define N_VIEWS 4
#define PATCH 40

// -2 * ln(0.001): g > 0.001  <=>  q < QMAX (the -10 clip only shrinks g further)
#define QMAX 13.815511f

// ---- tile renderer geometry ----
#define TILE 16
#define NTILES 1024                       // per view (32x32 tiles)
#define NTILES_ALL (N_VIEWS * NTILES)     // 4096
#define NBANDS 4                          // 4-row bands; one wave per band
#define NLISTS (NTILES_ALL * NBANDS)      // 16384
#define CAP_B 1024                        // per-band list cap; worst observed ~100
#define CHUNK 128                         // LDS staging chunk per band

#define COOP_GRID 512                     // 2 blocks/CU guaranteed by launch_bounds(256,2)

// ---- workspace layout (d_ws poisoned 0xAA each iteration by harness) ----
// counts : NLISTS int32                @ 0        (64 KB, zeroed by phase 0)
// params : NGAUSS*N_VIEWS * 8 float    @ 256 KB   (1.28 MB)
// lists  : NLISTS * CAP_B int32        @ 2 MB     (64 MB)
#define WS_PARAMS_OFF (256 * 1024)
#define WS_LISTS_OFF  (2 * 1024 * 1024)

__device__ __forceinline__ float fast_sigmoid(float x) {
    return 1.0f / (1.0f + __expf(-x));
}

// Bin one (splat, view): prep + project, emit 8-float param record, append id
// to each overlapped (tile, band) list. Bbox = exact ellipse AABB (+0.5 px fp
// safety) ∩ PATCH box ∩ image — a SUPERSET of contributing pixels; the exact
// reference mask (g>0.001 ∧ PATCH box) is re-tested per pixel at render.
__device__ __forceinline__ void bin_one(
    int t,
    const float* __restrict__ poses, const float* __restrict__ Km,
    const float* __restrict__ means, const float* __restrict__ log_scales,
    const float* __restrict__ quats, const float* __restrict__ shs,
    const float* __restrict__ opac,
    int* __restrict__ counts, float* __restrict__ params, int* __restrict__ lists)
{
    const int view = t / NGAUSS;
    const int n    = t - view * NGAUSS;

    const float m0 = means[n * 3 + 0];
    const float m1 = means[n * 3 + 1];
    const float m2 = means[n * 3 + 2];

    const float qw = quats[n * 4 + 0];
    const float qx = quats[n * 4 + 1];
    const float qy = quats[n * 4 + 2];
    const float qz = quats[n * 4 + 3];
    const float R00 = 1.0f - 2.0f * (qy * qy + qz * qz);
    const float R01 = 2.0f * (qx * qy - qw * qz);
    const float R02 = 2.0f * (qx * qz + qw * qy);
    const float R10 = 2.0f * (qx * qy + qw * qz);
    const float R11 = 1.0f - 2.0f * (qx * qx + qz * qz);
    const float R12 = 2.0f * (qy * qz - qw * qx);

    const float s0 = __expf(log_scales[n * 3 + 0]);
    const float s1 = __expf(log_scales[n * 3 + 1]);
    const float s2 = __expf(log_scales[n * 3 + 2]);

    const float a  = R00 * R00 * s0 + R01 * R01 * s1 + R02 * R02 * s2;
    const float b  = R00 * R10 * s0 + R01 * R11 * s1 + R02 * R12 * s2;
    const float dd = R10 * R10 * s0 + R11 * R11 * s1 + R12 * R12 * s2;

    const float det = a * dd - b * b;
    const float i00 =  dd / det;
    const float i01 = -b  / det;
    const float i11 =  a  / det;

    const float rx = sqrtf(QMAX * a)  + 0.5f;
    const float ry = sqrtf(QMAX * dd) + 0.5f;

    const float op = fast_sigmoid(opac[n]);
    const float w0 = op * fast_sigmoid(shs[n * 48 +  0]);
    const float w1 = op * fast_sigmoid(shs[n * 48 + 16]);
    const float w2 = op * fast_sigmoid(shs[n * 48 + 32]);

    const float* P = poses + view * 16;
    const float Xc = P[0] * m0 + P[1] * m1 + P[2]  * m2 + P[3];
    const float Yc = P[4] * m0 + P[5] * m1 + P[6]  * m2 + P[7];
    const float Zc = P[8] * m0 + P[9] * m1 + P[10] * m2 + P[11];

    const float ppx = Km[0] * Xc + Km[1] * Yc + Km[2] * Zc;
    const float ppy = Km[3] * Xc + Km[4] * Yc + Km[5] * Zc;
    const float ppz = Km[6] * Xc + Km[7] * Yc + Km[8] * Zc;

    const float denom = ppz + 1e-8f;
    const float uvx = ppx / denom;
    const float uvy = ppy / denom;

    const int u = (int)uvx;   // trunc, matches jnp.trunc + int32 cast
    const int v = (int)uvy;

    if (!((Zc >= 0.1f) && (u >= 0) && (u < IMG_W) && (v >= 0) && (v < IMG_H)))
        return;

    int xlo = (int)ceilf (uvx - rx);
    int xhi = (int)floorf(uvx + rx);
    int ylo = (int)ceilf (uvy - ry);
    int yhi = (int)floorf(uvy + ry);
    xlo = max(xlo, max(u - PATCH / 2, 0));
    xhi = min(xhi, min(u + PATCH / 2 - 1, IMG_W - 1));
    ylo = max(ylo, max(v - PATCH / 2, 0));
    yhi = min(yhi, min(v + PATCH / 2 - 1, IMG_H - 1));
    if (xhi < xlo || yhi < ylo) return;

    float4* rec = reinterpret_cast<float4*>(params + (size_t)t * 8);
    rec[0] = make_float4(uvx, uvy, i00, i01);
    rec[1] = make_float4(i11, w0,  w1,  w2);

    const int tx0 = xlo >> 4, tx1 = xhi >> 4;
    const int ty0 = ylo >> 4, ty1 = yhi >> 4;
    for (int ty = ty0; ty <= ty1; ++ty) {
        const int rlo = max(ylo - (ty << 4), 0) >> 2;       // 0..3
        const int rhi = min(yhi - (ty << 4), 15) >> 2;      // 0..3, >= rlo
        for (int tx = tx0; tx <= tx1; ++tx) {
            const int listBase = (((view << 10) | (ty << 5) | tx) << 2);
            for (int bb = rlo; bb <= rhi; ++bb) {
                const int idx = atomicAdd(&counts[listBase + bb], 1);
                if (idx < CAP_B) lists[(size_t)(listBase + bb) * CAP_B + idx] = t;
            }
        }
    }
}

// Render one (view, tile): wave w owns row-band w (4 rows x 16 cols = 64
// lanes), walks ONLY its band's list. Chunks of 128 staged to wave-private
// LDS (coalesced id load + params float4 gather), evaluated as broadcasts.
// Plain stores — zero fp32 atomics on the image.
__device__ __forceinline__ void render_tile(
    int tileId, int w, int lane,
    const int* __restrict__ counts, const float* __restrict__ params,
    const int* __restrict__ lists, float* __restrict__ out,
    float4 (&s_p0)[NBANDS][CHUNK], float4 (&s_p1)[NBANDS][CHUNK])
{
    const int view = tileId >> 10;
    const int tl   = tileId & (NTILES - 1);
    const int px   = ((tl & 31) << 4) + (lane & 15);
    const int py   = ((tl >> 5) << 4) + (w << 2) + (lane >> 4);
    const float fx = (float)px;
    const float fy = (float)py;

    const int listId = (tileId << 2) + w;
    // acquire-load: orders/invalidates vs bin-phase writes (fused path)
    int cnt = __hip_atomic_load(&counts[listId], __ATOMIC_ACQUIRE,
                                __HIP_MEMORY_SCOPE_AGENT);
    cnt = min(cnt, CAP_B);

    const int* __restrict__ lst = lists + (size_t)listId * CAP_B;

    float cr = 0.0f, cg_ = 0.0f, cb = 0.0f;
    for (int base = 0; base < cnt; base += CHUNK) {
        const int m = min(CHUNK, cnt - base);
        for (int j = lane; j < m; j += 64) {
            const int id = lst[base + j];                      // coalesced
            const float4* p4 =
                reinterpret_cast<const float4*>(params + (size_t)id * 8);
            s_p0[w][j] = p4[0];            // uvx uvy i00 i01
            s_p1[w][j] = p4[1];            // i11 w0  w1  w2
        }
        __threadfence_block();             // same-wave LDS write->read order

        for (int i = 0; i < m; ++i) {
            const float4 p0 = s_p0[w][i];  // LDS broadcast
            const float4 p1 = s_p1[w][i];

            const float dx = fx - p0.x;
            const float dy = fy - p0.y;
            const float q  = p0.z * dx * dx + 2.0f * p0.w * dx * dy + p1.x * dy * dy;
            const float g  = __expf(fminf(fmaxf(-0.5f * q, -10.0f), 0.0f));

            // exact reference mask: g-threshold ∧ PATCH box around (u,v)
            const int u = (int)p0.x;
            const int v = (int)p0.y;
            const bool ok = (g > 0.001f)
                          & (px >= u - PATCH / 2) & (px <= u + PATCH / 2 - 1)
                          & (py >= v - PATCH / 2) & (py <= v + PATCH / 2 - 1);
            if (ok) {
                cr  += g * p1.y;
                cg_ += g * p1.z;
                cb  += g * p1.w;
            }
        }
        __threadfence_block();             // drain reads before next overwrite
    }

    float* o = out + (((size_t)view * IMG_H + py) * IMG_W + px) * 3;
    o[0] = cr; o[1] = cg_; o[2] = cb;
}

// MODE 0: fused cooperative (zero -> sync -> bin -> sync -> render)
// MODE 1: zero + bin only (fallback, kernel boundary provides the sync)
// MODE 2: render only (fallback)
template <int MODE>
__global__ __launch_bounds__(256, 2) void gs_pipeline(
    const float* __restrict__ poses,
    const float* __restrict__ Km,
    const float* __restrict__ means,
    const float* __restrict__ log_scales,
    const float* __restrict__ quats,
    const float* __restrict__ shs,
    const float* __restrict__ opac,
    int*   __restrict__ counts,
    float* __restrict__ params,
    int*   __restrict__ lists,
    float* __restrict__ out)
{
    __shared__ float4 s_p0[NBANDS][CHUNK];
    __shared__ float4 s_p1[NBANDS][CHUNK];

    if (MODE != 2) {
        const int tid    = blockIdx.x * 256 + threadIdx.x;
        const int stride = gridDim.x * 256;

        // phase 0: zero counters (they live in poisoned workspace)
        for (int i = tid; i < NLISTS; i += stride) counts[i] = 0;
        if (MODE == 0) { __threadfence(); cg::this_grid().sync(); }

        // phase 1: bin
        for (int t = tid; t < NGAUSS * N_VIEWS; t += stride)
            bin_one(t, poses, Km, means, log_scales, quats, shs, opac,
                    counts, params, lists);
        if (MODE == 0) { __threadfence(); cg::this_grid().sync(); }
    }

    if (MODE != 1) {
        const int w    = threadIdx.x >> 6;     // wave id == band id
        const int lane = threadIdx.x & 63;
        for (int tile = blockIdx.x; tile < NTILES_ALL; tile += gridDim.x)
            render_tile(tile, w, lane, counts, params, lists, out, s_p0, s_p1);
    }
}

extern "C" void kernel_launch(void* const* d_in, const int* in_sizes, int n_in,
                              void* d_out, int out_size, void* d_ws, size_t ws_size,
                              hipStream_t stream) {
    const float* poses      = (const float*)d_in[0];
    const float* intrinsics = (const float*)d_in[1];
    const float* means      = (const float*)d_in[2];
    const float* log_scales = (const float*)d_in[3];
    const float* quats      = (const float*)d_in[4];
    const float* shs        = (const float*)d_in[5];
    const float* opac       = (const float*)d_in[6];
    float* out = (float*)d_out;

    int*   counts = (int*)d_ws;
    float* params = (float*)((char*)d_ws + WS_PARAMS_OFF);
    int*   lists  = (int*)((char*)d_ws + WS_LISTS_OFF);

    void* args[] = {
        (void*)&poses, (void*)&intrinsics, (void*)&means, (void*)&log_scales,
        (void*)&quats, (void*)&shs, (void*)&opac,
        (void*)&counts, (void*)&params, (void*)&lists, (void*)&out
    };

    hipError_t err = hipLaunchCooperativeKernel(
        gs_pipeline<0>, dim3(COOP_GRID), dim3(256), args, 0u, stream);

    if (err != hipSuccess) {
        (void)hipGetLastError();   // clear error state; fall back to 2 dispatches
        gs_pipeline<1><<<(NGAUSS * N_VIEWS + 255) / 256, 256, 0, stream>>>(
            poses, intrinsics, means, log_scales, quats, shs, opac,
            counts, params, lists, out);
        gs_pipeline<2><<<NTILES_ALL, 256, 0, stream>>>(
            poses, intrinsics, means, log_scales, quats, shs, opac,
            counts, params, lists, out);
    }
}

// Round 5
// 117.457 us; speedup vs baseline: 3.1731x; 3.1731x over previous
//
#include <hip/hip_runtime.h>

#define IMG_H 512
#define IMG_W 512
#define NGAUSS 10000
#define N_VIEWS 4
#define PATCH 40

// -2 * ln(0.001): g > 0.001  <=>  q < QMAX (the -10 clip only shrinks g further)
#define QMAX 13.815511f

// Block = (view, 8-row band). 4 views x 64 bands = 256 blocks = 1 per CU.
#define BAND_ROWS 8
#define NBANDS_IMG (IMG_H / BAND_ROWS)        // 64
#define NBLOCKS (N_VIEWS * NBANDS_IMG)        // 256
#define QCAP 3072                             // survivor queue; worst band ~900
#define IMG_FLOATS (BAND_ROWS * IMG_W * 3)    // 12288 floats = 49152 B

__device__ __forceinline__ float fast_sigmoid(float x) {
    return 1.0f / (1.0f + __expf(-x));
}

// Single kernel, single graph node, NO workspace, NO global atomics.
// Per block: zero LDS band image -> scan all splats of its view with a cheap
// row-extent test (compact survivors to LDS queue) -> full-lane eval of
// survivors with LDS float atomics -> coalesced plain-store dump of the band.
// Rows are partitioned exactly across blocks, so d_out is written once each.
// The scan's row window is the exact ellipse AABB (+0.5 px fp safety) ∩ PATCH
// box ∩ image — a SUPERSET of contributing rows (outside it, min-q over dx
// exceeds QMAX => g <= 0.001, or the PATCH/image mask fails); the exact
// reference mask (g>0.001 ∧ PATCH box) is re-tested per pixel in eval.
__global__ __launch_bounds__(256) void gs_band_kernel(
    const float* __restrict__ poses,
    const float* __restrict__ Km,
    const float* __restrict__ means,
    const float* __restrict__ log_scales,
    const float* __restrict__ quats,
    const float* __restrict__ shs,
    const float* __restrict__ opac,
    float* __restrict__ out)
{
    __shared__ float s_img[IMG_FLOATS];     // 49152 B band image
    __shared__ int   s_queue[QCAP];         // 12288 B survivor ids
    __shared__ int   s_qn;                  // total: 61444 B (< 64 KB static)

    const int view = blockIdx.x >> 6;
    const int y0   = (blockIdx.x & 63) << 3;     // first row of this band
    const int tid  = threadIdx.x;

    // ---- phase 0: zero LDS ----
    float4* img4 = reinterpret_cast<float4*>(s_img);
    #pragma unroll
    for (int i = 0; i < IMG_FLOATS / 4 / 256; ++i)
        img4[i * 256 + tid] = make_float4(0.f, 0.f, 0.f, 0.f);
    if (tid == 0) s_qn = 0;
    __syncthreads();

    // wave-uniform camera constants (compiler emits scalar loads)
    const float* P = poses + view * 16;
    const float P0 = P[0], P1 = P[1], P2  = P[2],  P3  = P[3];
    const float P4 = P[4], P5 = P[5], P6  = P[6],  P7  = P[7];
    const float P8 = P[8], P9 = P[9], P10 = P[10], P11 = P[11];
    const float K0 = Km[0], K1 = Km[1], K2 = Km[2];
    const float K3 = Km[3], K4 = Km[4], K5 = Km[5];
    const float K6 = Km[6], K7 = Km[7], K8 = Km[8];

    // ---- phase 1: scan all splats of this view, cheap row-extent test ----
    for (int n = tid; n < NGAUSS; n += 256) {
        const float m0 = means[n * 3 + 0];
        const float m1 = means[n * 3 + 1];
        const float m2 = means[n * 3 + 2];

        const float Xc = P0 * m0 + P1 * m1 + P2  * m2 + P3;
        const float Yc = P4 * m0 + P5 * m1 + P6  * m2 + P7;
        const float Zc = P8 * m0 + P9 * m1 + P10 * m2 + P11;

        const float ppx = K0 * Xc + K1 * Yc + K2 * Zc;
        const float ppy = K3 * Xc + K4 * Yc + K5 * Zc;
        const float ppz = K6 * Xc + K7 * Yc + K8 * Zc;

        const float denom = ppz + 1e-8f;
        const float uvx = ppx / denom;
        const float uvy = ppy / denom;

        const int u = (int)uvx;   // trunc, matches jnp.trunc + int32 cast
        const int v = (int)uvy;

        if (!((Zc >= 0.1f) && (u >= 0) && (u < IMG_W) && (v >= 0) && (v < IMG_H)))
            continue;

        // vertical extent only: dd = row1 . diag(s) . row1
        const float4 qv = *reinterpret_cast<const float4*>(quats + n * 4);
        const float qw = qv.x, qx = qv.y, qy = qv.z, qz = qv.w;
        const float R10 = 2.0f * (qx * qy + qw * qz);
        const float R11 = 1.0f - 2.0f * (qx * qx + qz * qz);
        const float R12 = 2.0f * (qy * qz - qw * qx);

        const float s0 = __expf(log_scales[n * 3 + 0]);
        const float s1 = __expf(log_scales[n * 3 + 1]);
        const float s2 = __expf(log_scales[n * 3 + 2]);

        const float dd = R10 * R10 * s0 + R11 * R11 * s1 + R12 * R12 * s2;
        const float ry = sqrtf(QMAX * dd) + 0.5f;

        const int ylo = max((int)ceilf (uvy - ry), max(v - PATCH / 2, 0));
        const int yhi = min((int)floorf(uvy + ry), min(v + PATCH / 2 - 1, IMG_H - 1));
        if (ylo > yhi || ylo > y0 + (BAND_ROWS - 1) || yhi < y0)
            continue;                                   // no overlap with band

        const int idx = atomicAdd(&s_qn, 1);
        if (idx < QCAP) s_queue[idx] = n;
    }
    __syncthreads();

    const int qn = min(s_qn, QCAP);

    // ---- phase 2: full-lane eval of survivors (LDS float atomics) ----
    for (int i = tid; i < qn; i += 256) {
        const int n = s_queue[i];

        const float m0 = means[n * 3 + 0];
        const float m1 = means[n * 3 + 1];
        const float m2 = means[n * 3 + 2];

        const float4 qv = *reinterpret_cast<const float4*>(quats + n * 4);
        const float qw = qv.x, qx = qv.y, qy = qv.z, qz = qv.w;
        const float R00 = 1.0f - 2.0f * (qy * qy + qz * qz);
        const float R01 = 2.0f * (qx * qy - qw * qz);
        const float R02 = 2.0f * (qx * qz + qw * qy);
        const float R10 = 2.0f * (qx * qy + qw * qz);
        const float R11 = 1.0f - 2.0f * (qx * qx + qz * qz);
        const float R12 = 2.0f * (qy * qz - qw * qx);

        const float s0 = __expf(log_scales[n * 3 + 0]);
        const float s1 = __expf(log_scales[n * 3 + 1]);
        const float s2 = __expf(log_scales[n * 3 + 2]);

        const float a  = R00 * R00 * s0 + R01 * R01 * s1 + R02 * R02 * s2;
        const float b  = R00 * R10 * s0 + R01 * R11 * s1 + R02 * R12 * s2;
        const float dd = R10 * R10 * s0 + R11 * R11 * s1 + R12 * R12 * s2;

        const float det = a * dd - b * b;
        const float i00 =  dd / det;
        const float i01 = -b  / det;
        const float i11 =  a  / det;

        const float rx = sqrtf(QMAX * a)  + 0.5f;
        const float ry = sqrtf(QMAX * dd) + 0.5f;

        const float op = fast_sigmoid(opac[n]);
        const float w0 = op * fast_sigmoid(shs[n * 48 +  0]);
        const float w1 = op * fast_sigmoid(shs[n * 48 + 16]);
        const float w2 = op * fast_sigmoid(shs[n * 48 + 32]);

        const float Xc = P0 * m0 + P1 * m1 + P2  * m2 + P3;
        const float Yc = P4 * m0 + P5 * m1 + P6  * m2 + P7;
        const float Zc = P8 * m0 + P9 * m1 + P10 * m2 + P11;
        const float ppx = K0 * Xc + K1 * Yc + K2 * Zc;
        const float ppy = K3 * Xc + K4 * Yc + K5 * Zc;
        const float ppz = K6 * Xc + K7 * Yc + K8 * Zc;
        const float denom = ppz + 1e-8f;
        const float uvx = ppx / denom;
        const float uvy = ppy / denom;
        const int u = (int)uvx;
        const int v = (int)uvy;

        const int xlo = max((int)ceilf (uvx - rx), max(u - PATCH / 2, 0));
        const int xhi = min((int)floorf(uvx + rx), min(u + PATCH / 2 - 1, IMG_W - 1));
        const int ylo = max(max((int)ceilf (uvy - ry), max(v - PATCH / 2, 0)), y0);
        const int yhi = min(min((int)floorf(uvy + ry),
                                min(v + PATCH / 2 - 1, IMG_H - 1)),
                            y0 + (BAND_ROWS - 1));

        for (int yy = ylo; yy <= yhi; ++yy) {
            const float dy = (float)yy - uvy;
            const float qy2  = i11 * dy * dy;
            const float qy1  = 2.0f * i01 * dy;
            float* row = s_img + (size_t)(yy - y0) * (IMG_W * 3);
            for (int xx = xlo; xx <= xhi; ++xx) {
                const float dx = (float)xx - uvx;
                const float q  = i00 * dx * dx + qy1 * dx + qy2;
                const float g  = __expf(fminf(fmaxf(-0.5f * q, -10.0f), 0.0f));
                if (g > 0.001f) {       // exact reference mask (PATCH box already enforced)
                    atomicAdd(row + xx * 3 + 0, g * w0);
                    atomicAdd(row + xx * 3 + 1, g * w1);
                    atomicAdd(row + xx * 3 + 2, g * w2);
                }
            }
        }
    }
    __syncthreads();

    // ---- phase 3: coalesced dump of the band (plain stores, rows disjoint) ----
    float4* o4 = reinterpret_cast<float4*>(
        out + ((size_t)view * IMG_H + y0) * (IMG_W * 3));
    #pragma unroll
    for (int i = 0; i < IMG_FLOATS / 4 / 256; ++i)
        o4[i * 256 + tid] = img4[i * 256 + tid];
}

extern "C" void kernel_launch(void* const* d_in, const int* in_sizes, int n_in,
                              void* d_out, int out_size, void* d_ws, size_t ws_size,
                              hipStream_t stream) {
    const float* poses      = (const float*)d_in[0];
    const float* intrinsics = (const float*)d_in[1];
    const float* means      = (const float*)d_in[2];
    const float* log_scales = (const float*)d_in[3];
    const float* quats      = (const float*)d_in[4];
    const float* shs        = (const float*)d_in[5];
    const float* opac       = (const float*)d_in[6];
    float* out = (float*)d_out;

    // ONE kernel node, no workspace, no global atomics.
    gs_band_kernel<<<NBLOCKS, 256, 0, stream>>>(
        poses, intrinsics, means, log_scales, quats, shs, opac, out);
}

// Round 6
// 92.564 us; speedup vs baseline: 4.0264x; 1.2689x over previous
//
#include <hip/hip_runtime.h>

#define IMG_H 512
#define IMG_W 512
#define NGAUSS 10000
#define N_VIEWS 4
#define PATCH 40

// -2 * ln(0.001): g > 0.001  <=>  q < QMAX (the -10 clip only shrinks g further)
#define QMAX 13.815511f

// Block = (view, 8-row band). 4 views x 64 bands = 256 blocks = 1 per CU.
// 1024 threads/block -> 16 waves/CU (4/SIMD) for latency hiding (R5 was 1/SIMD).
#define BLOCK_T 1024
#define BAND_ROWS 8
#define NBANDS_IMG (IMG_H / BAND_ROWS)        // 64
#define NBLOCKS (N_VIEWS * NBANDS_IMG)        // 256
#define QCAP 3072                             // survivor queue; worst band ~1100 w/ inflated bound
#define IMG_FLOATS (BAND_ROWS * IMG_W * 3)    // 12288 floats = 49152 B

__device__ __forceinline__ float fast_sigmoid(float x) {
    return 1.0f / (1.0f + __expf(-x));
}

// Single kernel, single graph node, NO workspace, NO global atomics.
// Per block: zero LDS band image -> scan all splats of its view with a cheap
// row-extent test (compact survivors to LDS queue) -> full-lane eval of
// survivors with LDS float atomics -> coalesced plain-store dump of the band.
// Rows are partitioned exactly across blocks, so d_out is written once each.
//
// Scan row window uses the UPPER BOUND dd <= max(s0,s1,s2) (since
// dd = sum R1j^2 * sj with sum R1j^2 = 1) => ry_ub >= ry_true: a SUPERSET of
// contributing rows. Eval recomputes the exact ellipse AABB ∩ PATCH box ∩
// image and re-tests the exact reference mask (g>0.001 ∧ PATCH box) per
// pixel, so binning slack never changes results.
__global__ __launch_bounds__(BLOCK_T) void gs_band_kernel(
    const float* __restrict__ poses,
    const float* __restrict__ Km,
    const float* __restrict__ means,
    const float* __restrict__ log_scales,
    const float* __restrict__ quats,
    const float* __restrict__ shs,
    const float* __restrict__ opac,
    float* __restrict__ out)
{
    __shared__ float s_img[IMG_FLOATS];     // 49152 B band image
    __shared__ int   s_queue[QCAP];         // 12288 B survivor ids
    __shared__ int   s_qn;                  // total: 61444 B (< 64 KB static)

    const int view = blockIdx.x >> 6;
    const int y0   = (blockIdx.x & 63) << 3;     // first row of this band
    const int tid  = threadIdx.x;

    // ---- phase 0: zero LDS ----
    float4* img4 = reinterpret_cast<float4*>(s_img);
    #pragma unroll
    for (int i = 0; i < IMG_FLOATS / 4 / BLOCK_T; ++i)
        img4[i * BLOCK_T + tid] = make_float4(0.f, 0.f, 0.f, 0.f);
    if (tid == 0) s_qn = 0;
    __syncthreads();

    // wave-uniform camera constants (compiler emits scalar loads)
    const float* P = poses + view * 16;
    const float P0 = P[0], P1 = P[1], P2  = P[2],  P3  = P[3];
    const float P4 = P[4], P5 = P[5], P6  = P[6],  P7  = P[7];
    const float P8 = P[8], P9 = P[9], P10 = P[10], P11 = P[11];
    const float K0 = Km[0], K1 = Km[1], K2 = Km[2];
    const float K3 = Km[3], K4 = Km[4], K5 = Km[5];
    const float K6 = Km[6], K7 = Km[7], K8 = Km[8];

    // ---- phase 1: scan all splats of this view, cheap row-extent test ----
    for (int n = tid; n < NGAUSS; n += BLOCK_T) {
        const float m0 = means[n * 3 + 0];
        const float m1 = means[n * 3 + 1];
        const float m2 = means[n * 3 + 2];

        const float Xc = P0 * m0 + P1 * m1 + P2  * m2 + P3;
        const float Yc = P4 * m0 + P5 * m1 + P6  * m2 + P7;
        const float Zc = P8 * m0 + P9 * m1 + P10 * m2 + P11;

        const float ppx = K0 * Xc + K1 * Yc + K2 * Zc;
        const float ppy = K3 * Xc + K4 * Yc + K5 * Zc;
        const float ppz = K6 * Xc + K7 * Yc + K8 * Zc;

        const float rcp = 1.0f / (ppz + 1e-8f);
        const float uvx = ppx * rcp;
        const float uvy = ppy * rcp;

        const int u = (int)uvx;   // trunc, matches jnp.trunc + int32 cast
        const int v = (int)uvy;

        if (!((Zc >= 0.1f) && (u >= 0) && (u < IMG_W) && (v >= 0) && (v < IMG_H)))
            continue;             // validity is load-bearing: eval assumes it

        // upper-bound vertical extent: dd <= exp(max log_scale)
        const float ls0 = log_scales[n * 3 + 0];
        const float ls1 = log_scales[n * 3 + 1];
        const float ls2 = log_scales[n * 3 + 2];
        const float ry  = sqrtf(QMAX * __expf(fmaxf(fmaxf(ls0, ls1), ls2))) + 0.5f;

        const int ylo = max((int)ceilf (uvy - ry), max(v - PATCH / 2, 0));
        const int yhi = min((int)floorf(uvy + ry), min(v + PATCH / 2 - 1, IMG_H - 1));
        if (ylo > yhi || ylo > y0 + (BAND_ROWS - 1) || yhi < y0)
            continue;                                   // no overlap with band

        const int idx = atomicAdd(&s_qn, 1);
        if (idx < QCAP) s_queue[idx] = n;
    }
    __syncthreads();

    const int qn = min(s_qn, QCAP);

    // ---- phase 2: full-lane eval of survivors (exact window, LDS atomics) ----
    for (int i = tid; i < qn; i += BLOCK_T) {
        const int n = s_queue[i];

        const float m0 = means[n * 3 + 0];
        const float m1 = means[n * 3 + 1];
        const float m2 = means[n * 3 + 2];

        const float4 qv = *reinterpret_cast<const float4*>(quats + n * 4);
        const float qw = qv.x, qx = qv.y, qy = qv.z, qz = qv.w;
        const float R00 = 1.0f - 2.0f * (qy * qy + qz * qz);
        const float R01 = 2.0f * (qx * qy - qw * qz);
        const float R02 = 2.0f * (qx * qz + qw * qy);
        const float R10 = 2.0f * (qx * qy + qw * qz);
        const float R11 = 1.0f - 2.0f * (qx * qx + qz * qz);
        const float R12 = 2.0f * (qy * qz - qw * qx);

        const float s0 = __expf(log_scales[n * 3 + 0]);
        const float s1 = __expf(log_scales[n * 3 + 1]);
        const float s2 = __expf(log_scales[n * 3 + 2]);

        const float a  = R00 * R00 * s0 + R01 * R01 * s1 + R02 * R02 * s2;
        const float b  = R00 * R10 * s0 + R01 * R11 * s1 + R02 * R12 * s2;
        const float dd = R10 * R10 * s0 + R11 * R11 * s1 + R12 * R12 * s2;

        const float det = a * dd - b * b;
        const float i00 =  dd / det;
        const float i01 = -b  / det;
        const float i11 =  a  / det;

        const float rx = sqrtf(QMAX * a)  + 0.5f;
        const float ry = sqrtf(QMAX * dd) + 0.5f;

        const float op = fast_sigmoid(opac[n]);
        const float w0 = op * fast_sigmoid(shs[n * 48 +  0]);
        const float w1 = op * fast_sigmoid(shs[n * 48 + 16]);
        const float w2 = op * fast_sigmoid(shs[n * 48 + 32]);

        const float Xc = P0 * m0 + P1 * m1 + P2  * m2 + P3;
        const float Yc = P4 * m0 + P5 * m1 + P6  * m2 + P7;
        const float Zc = P8 * m0 + P9 * m1 + P10 * m2 + P11;
        const float ppx = K0 * Xc + K1 * Yc + K2 * Zc;
        const float ppy = K3 * Xc + K4 * Yc + K5 * Zc;
        const float ppz = K6 * Xc + K7 * Yc + K8 * Zc;
        const float rcp = 1.0f / (ppz + 1e-8f);
        const float uvx = ppx * rcp;
        const float uvy = ppy * rcp;
        const int u = (int)uvx;
        const int v = (int)uvy;

        const int xlo = max((int)ceilf (uvx - rx), max(u - PATCH / 2, 0));
        const int xhi = min((int)floorf(uvx + rx), min(u + PATCH / 2 - 1, IMG_W - 1));
        const int ylo = max(max((int)ceilf (uvy - ry), max(v - PATCH / 2, 0)), y0);
        const int yhi = min(min((int)floorf(uvy + ry),
                                min(v + PATCH / 2 - 1, IMG_H - 1)),
                            y0 + (BAND_ROWS - 1));

        for (int yy = ylo; yy <= yhi; ++yy) {
            const float dy = (float)yy - uvy;
            const float qy2  = i11 * dy * dy;
            const float qy1  = 2.0f * i01 * dy;
            float* row = s_img + (size_t)(yy - y0) * (IMG_W * 3);
            for (int xx = xlo; xx <= xhi; ++xx) {
                const float dx = (float)xx - uvx;
                const float q  = i00 * dx * dx + qy1 * dx + qy2;
                const float g  = __expf(fminf(fmaxf(-0.5f * q, -10.0f), 0.0f));
                if (g > 0.001f) {       // exact reference mask (PATCH box already enforced)
                    atomicAdd(row + xx * 3 + 0, g * w0);
                    atomicAdd(row + xx * 3 + 1, g * w1);
                    atomicAdd(row + xx * 3 + 2, g * w2);
                }
            }
        }
    }
    __syncthreads();

    // ---- phase 3: coalesced dump of the band (plain stores, rows disjoint) ----
    float4* o4 = reinterpret_cast<float4*>(
        out + ((size_t)view * IMG_H + y0) * (IMG_W * 3));
    #pragma unroll
    for (int i = 0; i < IMG_FLOATS / 4 / BLOCK_T; ++i)
        o4[i * BLOCK_T + tid] = img4[i * BLOCK_T + tid];
}

extern "C" void kernel_launch(void* const* d_in, const int* in_sizes, int n_in,
                              void* d_out, int out_size, void* d_ws, size_t ws_size,
                              hipStream_t stream) {
    const float* poses      = (const float*)d_in[0];
    const float* intrinsics = (const float*)d_in[1];
    const float* means      = (const float*)d_in[2];
    const float* log_scales = (const float*)d_in[3];
    const float* quats      = (const float*)d_in[4];
    const float* shs        = (const float*)d_in[5];
    const float* opac       = (const float*)d_in[6];
    float* out = (float*)d_out;

    // ONE kernel node, no workspace, no global atomics.
    gs_band_kernel<<<NBLOCKS, BLOCK_T, 0, stream>>>(
        poses, intrinsics, means, log_scales, quats, shs, opac, out);
}